// Round 1
// baseline (425.181 us; speedup 1.0000x reference)
//
#include <hip/hip_runtime.h>

typedef unsigned short u16;
typedef __attribute__((ext_vector_type(8))) short short8;
typedef __attribute__((ext_vector_type(4))) float f32x4;
typedef __attribute__((ext_vector_type(4))) unsigned short u16x4;

__device__ __forceinline__ u16 f2bf(float f){
  unsigned u = __float_as_uint(f);
  u += 0x7FFFu + ((u >> 16) & 1u);
  return (u16)(u >> 16);
}
__device__ __forceinline__ float bf2f(u16 h){
  return __uint_as_float(((unsigned)h) << 16);
}
__device__ __forceinline__ void gload16(const void* g, void* l){
  __builtin_amdgcn_global_load_lds((const __attribute__((address_space(1))) void*)g,
                                   (__attribute__((address_space(3))) void*)l, 16, 0, 0);
}
__device__ __forceinline__ f32x4 mfma16(short8 a, short8 b, f32x4 c){
  return __builtin_amdgcn_mfma_f32_16x16x32_bf16(a, b, c, 0, 0, 0);
}

// ---------------- f32 -> bf16 convert (vectorized) ----------------
__global__ void cvt_f32_bf16(const float* __restrict__ s, u16* __restrict__ d, int n4){
  int i = blockIdx.x * 256 + threadIdx.x;
  if (i >= n4) return;
  float4 v = reinterpret_cast<const float4*>(s)[i];
  u16x4 o = { f2bf(v.x), f2bf(v.y), f2bf(v.z), f2bf(v.w) };
  reinterpret_cast<u16x4*>(d)[i] = o;
}

// ---------------- transpose-convert: per head [K][C] f32 -> [C][K] bf16 ----------------
__global__ void transpose_f32_bf16(const float* __restrict__ s, u16* __restrict__ d,
                                   int K, int C){
  __shared__ float t[32][33];
  size_t hoff = (size_t)blockIdx.z * K * C;
  const float* S = s + hoff;
  u16* D = d + hoff;
  int kb = blockIdx.x * 32, cb = blockIdx.y * 32;
  int tx = threadIdx.x, ty = threadIdx.y;
  #pragma unroll
  for (int i = ty; i < 32; i += 8)
    t[i][tx] = S[(size_t)(kb + i) * C + cb + tx];
  __syncthreads();
  #pragma unroll
  for (int i = ty; i < 32; i += 8)
    D[(size_t)(cb + i) * K + kb + tx] = f2bf(t[tx][i]);
}

// ---------------- bf16 GEMM, 128x128 tile, BK=32, global_load_lds ----------------
// A: [M][Kd] row-major bf16 with segment row-remap (phys = (r/aS)*aT + r%aS + aOff)
// BT: [N][Kd] row-major bf16 (i.e. B transposed)
// C: bf16 (Cb) or f32 (Cf), ldc, with row remap (cS,cT,cOff)
__global__ __launch_bounds__(256)
void gemm_bf16(const u16* __restrict__ A, int lda, int aS, int aT, int aOff,
               const u16* __restrict__ BT, int ldbt,
               u16* __restrict__ Cb, float* __restrict__ Cf, int ldc,
               int cS, int cT, int cOff, int N, int Kd){
  __shared__ __align__(16) u16 As[128*32];
  __shared__ __align__(16) u16 Bs[128*32];
  int ntx = N >> 7;
  int bm = blockIdx.x / ntx;
  int bn = blockIdx.x - bm * ntx;
  int row0 = bm << 7, col0 = bn << 7;
  size_t arow0 = (size_t)(row0 / aS) * aT + (row0 % aS) + aOff;
  size_t crow0 = (size_t)(row0 / cS) * cT + (row0 % cS) + cOff;
  const u16* Abase = A + arow0 * (size_t)lda;
  const u16* Bbase = BT + (size_t)col0 * ldbt;
  int tid = threadIdx.x;
  int w = tid >> 6, l = tid & 63;
  int wr = (w >> 1) << 6, wc = (w & 1) << 6;
  int lr = l & 15, lk = (l >> 4) << 3, lq = (l >> 4) << 2;
  f32x4 acc[4][4];
  #pragma unroll
  for (int m = 0; m < 4; m++)
    #pragma unroll
    for (int n = 0; n < 4; n++)
      acc[m][n] = (f32x4){0.f, 0.f, 0.f, 0.f};
  const u16* gA = Abase + (size_t)(tid >> 2) * lda + ((tid & 3) << 3);
  const u16* gB = Bbase + (size_t)(tid >> 2) * ldbt + ((tid & 3) << 3);
  char* lA = (char*)As + tid * 16;
  char* lB = (char*)Bs + tid * 16;
  size_t a64 = (size_t)64 * lda, b64 = (size_t)64 * ldbt;
  for (int k0 = 0; k0 < Kd; k0 += 32){
    gload16(gA + k0,       lA);
    gload16(gA + a64 + k0, lA + 4096);
    gload16(gB + k0,       lB);
    gload16(gB + b64 + k0, lB + 4096);
    __syncthreads();
    short8 af[4], bfr[4];
    #pragma unroll
    for (int m = 0; m < 4; m++)
      af[m] = *reinterpret_cast<const short8*>(&As[(wr + m*16 + lr)*32 + lk]);
    #pragma unroll
    for (int n = 0; n < 4; n++)
      bfr[n] = *reinterpret_cast<const short8*>(&Bs[(wc + n*16 + lr)*32 + lk]);
    #pragma unroll
    for (int m = 0; m < 4; m++)
      #pragma unroll
      for (int n = 0; n < 4; n++)
        acc[m][n] = mfma16(af[m], bfr[n], acc[m][n]);
    __syncthreads();
  }
  #pragma unroll
  for (int m = 0; m < 4; m++){
    #pragma unroll
    for (int i = 0; i < 4; i++){
      size_t r = crow0 + wr + m*16 + lq + i;
      if (Cb){
        #pragma unroll
        for (int n = 0; n < 4; n++)
          Cb[r*ldc + col0 + wc + n*16 + lr] = f2bf(acc[m][n][i]);
      } else {
        #pragma unroll
        for (int n = 0; n < 4; n++)
          Cf[r*ldc + col0 + wc + n*16 + lr] = acc[m][n][i];
      }
    }
  }
}

// ---------------- RoPE + k/v/idx outputs ----------------
// qbuf [B*T][2048] bf16 (8 heads x 256), kvbuf [B*T][512] bf16 (k|v)
__global__ void rope_kernel(u16* __restrict__ qbuf, u16* __restrict__ kvbuf,
                            const int* __restrict__ positions,
                            float* __restrict__ k_out, float* __restrict__ v_out,
                            float* __restrict__ idx_out){
  int bt = blockIdx.x;
  int j = threadIdx.x;           // 0..127 (half of H=256)
  float pos = (float)positions[bt];
  float ts = powf(10000.0f, (float)j * 0.0078125f);  // 10000^(j/128)
  float rad = pos / ts;
  float sn, cs;
  sincosf(rad, &sn, &cs);
  u16* q = qbuf + (size_t)bt * 2048;
  #pragma unroll
  for (int n = 0; n < 8; n++){
    float x1 = bf2f(q[n*256 + j]);
    float x2 = bf2f(q[n*256 + 128 + j]);
    q[n*256 + j]       = f2bf((x1*cs - x2*sn) * 0.0625f);   // * H^-0.5
    q[n*256 + 128 + j] = f2bf((x2*cs + x1*sn) * 0.0625f);
  }
  u16* kv = kvbuf + (size_t)bt * 512;
  float x1 = bf2f(kv[j]), x2 = bf2f(kv[128 + j]);
  float k1 = x1*cs - x2*sn, k2 = x2*cs + x1*sn;
  kv[j] = f2bf(k1); kv[128 + j] = f2bf(k2);
  size_t ko = (size_t)bt * 256;
  k_out[ko + j] = k1;  k_out[ko + 128 + j] = k2;
  v_out[ko + j] = bf2f(kv[256 + j]);
  v_out[ko + 128 + j] = bf2f(kv[384 + j]);
  if (bt == 0 && j < 4) idx_out[j] = 1024.0f;
}

// ---------------- transpose V: kvbuf[:, 256:512] -> vT [B][256][1024] ----------------
__global__ void transpose_v(const u16* __restrict__ kvbuf, u16* __restrict__ vT){
  __shared__ u16 t[32][33];
  int b = blockIdx.z;
  int tb = blockIdx.x * 32, hb = blockIdx.y * 32;
  int tx = threadIdx.x, ty = threadIdx.y;
  #pragma unroll
  for (int i = ty; i < 32; i += 8)
    t[i][tx] = kvbuf[(size_t)(b*1024 + tb + i)*512 + 256 + hb + tx];
  __syncthreads();
  #pragma unroll
  for (int i = ty; i < 32; i += 8)
    vT[(size_t)(b*256 + hb + i)*1024 + tb + tx] = t[tx][i];
}

// ---------------- flash attention: 1 wave/block, 32 q-rows, kv tile 32 ----------------
__global__ __launch_bounds__(64)
void attn_kernel(const u16* __restrict__ qbuf, const u16* __restrict__ kvbuf,
                 const u16* __restrict__ vT, u16* __restrict__ enc){
  int blk = blockIdx.x;
  int qt = blk & 31;
  int n  = (blk >> 5) & 7;
  int b  = blk >> 8;
  int l  = threadIdx.x;
  int lr = l & 15, lk = (l >> 4) << 3, lq = (l >> 4) << 2;
  int q0 = qt * 32;
  const u16* qb = qbuf + ((size_t)(b*1024 + q0)) * 2048 + n*256;
  short8 qf[2][8];
  #pragma unroll
  for (int rf = 0; rf < 2; rf++)
    #pragma unroll
    for (int hf = 0; hf < 8; hf++)
      qf[rf][hf] = *reinterpret_cast<const short8*>(&qb[(size_t)(rf*16 + lr)*2048 + hf*32 + lk]);
  f32x4 o[2][16];
  #pragma unroll
  for (int rf = 0; rf < 2; rf++)
    #pragma unroll
    for (int hf = 0; hf < 16; hf++)
      o[rf][hf] = (f32x4){0.f,0.f,0.f,0.f};
  float mrow[2][4], lrow[2][4];
  #pragma unroll
  for (int rf = 0; rf < 2; rf++)
    #pragma unroll
    for (int i = 0; i < 4; i++){ mrow[rf][i] = -3.0e38f; lrow[rf][i] = 0.f; }
  const u16* kb = kvbuf + (size_t)b * 1024 * 512;
  const u16* vb = vT + (size_t)b * 256 * 1024;
  __shared__ __align__(16) u16 P[32*32];
  for (int kt = 0; kt <= q0; kt += 32){
    f32x4 s[2][2];
    #pragma unroll
    for (int rf = 0; rf < 2; rf++)
      #pragma unroll
      for (int cf = 0; cf < 2; cf++)
        s[rf][cf] = (f32x4){0.f,0.f,0.f,0.f};
    #pragma unroll
    for (int hf = 0; hf < 8; hf++){
      short8 k0f = *reinterpret_cast<const short8*>(&kb[(size_t)(kt + lr)*512 + hf*32 + lk]);
      short8 k1f = *reinterpret_cast<const short8*>(&kb[(size_t)(kt + 16 + lr)*512 + hf*32 + lk]);
      s[0][0] = mfma16(qf[0][hf], k0f, s[0][0]);
      s[1][0] = mfma16(qf[1][hf], k0f, s[1][0]);
      s[0][1] = mfma16(qf[0][hf], k1f, s[0][1]);
      s[1][1] = mfma16(qf[1][hf], k1f, s[1][1]);
    }
    if (kt == q0){   // diagonal tile: mask col > row
      #pragma unroll
      for (int rf = 0; rf < 2; rf++)
        #pragma unroll
        for (int cf = 0; cf < 2; cf++)
          #pragma unroll
          for (int i = 0; i < 4; i++){
            int rl = rf*16 + lq + i, cl = cf*16 + lr;
            if (cl > rl) s[rf][cf][i] = -1.0e30f;
          }
    }
    #pragma unroll
    for (int rf = 0; rf < 2; rf++){
      float mx[4], sm[4];
      #pragma unroll
      for (int i = 0; i < 4; i++) mx[i] = fmaxf(s[rf][0][i], s[rf][1][i]);
      #pragma unroll
      for (int d = 1; d < 16; d <<= 1)
        #pragma unroll
        for (int i = 0; i < 4; i++) mx[i] = fmaxf(mx[i], __shfl_xor(mx[i], d, 64));
      #pragma unroll
      for (int i = 0; i < 4; i++){
        float mn = fmaxf(mrow[rf][i], mx[i]);
        float corr = __expf(mrow[rf][i] - mn);
        mrow[rf][i] = mn;
        s[rf][0][i] = __expf(s[rf][0][i] - mn);
        s[rf][1][i] = __expf(s[rf][1][i] - mn);
        sm[i] = s[rf][0][i] + s[rf][1][i];
        lrow[rf][i] *= corr;
        #pragma unroll
        for (int hf = 0; hf < 16; hf++) o[rf][hf][i] *= corr;
      }
      #pragma unroll
      for (int d = 1; d < 16; d <<= 1)
        #pragma unroll
        for (int i = 0; i < 4; i++) sm[i] += __shfl_xor(sm[i], d, 64);
      #pragma unroll
      for (int i = 0; i < 4; i++) lrow[rf][i] += sm[i];
    }
    // P (C-layout) -> LDS -> A-frag layout
    #pragma unroll
    for (int rf = 0; rf < 2; rf++)
      #pragma unroll
      for (int cf = 0; cf < 2; cf++)
        #pragma unroll
        for (int i = 0; i < 4; i++)
          P[(rf*16 + lq + i)*32 + cf*16 + lr] = f2bf(s[rf][cf][i]);
    __syncthreads();
    short8 pa0 = *reinterpret_cast<const short8*>(&P[lr*32 + lk]);
    short8 pa1 = *reinterpret_cast<const short8*>(&P[(16 + lr)*32 + lk]);
    #pragma unroll
    for (int hf = 0; hf < 16; hf++){
      short8 vf = *reinterpret_cast<const short8*>(&vb[(size_t)(hf*16 + lr)*1024 + kt + lk]);
      o[0][hf] = mfma16(pa0, vf, o[0][hf]);
      o[1][hf] = mfma16(pa1, vf, o[1][hf]);
    }
    __syncthreads();
  }
  u16* eb = enc + ((size_t)(b*1024 + q0)) * 2048 + n*256;
  #pragma unroll
  for (int rf = 0; rf < 2; rf++)
    #pragma unroll
    for (int hf = 0; hf < 16; hf++)
      #pragma unroll
      for (int i = 0; i < 4; i++)
        eb[(size_t)(rf*16 + lq + i)*2048 + hf*16 + lr] = f2bf(o[rf][hf][i] / lrow[rf][i]);
}

extern "C" void kernel_launch(void* const* d_in, const int* in_sizes, int n_in,
                              void* d_out, int out_size, void* d_ws, size_t ws_size,
                              hipStream_t stream){
  const float* x0     = (const float*)d_in[0];
  const float* x1     = (const float*)d_in[1];
  const int*   pos    = (const int*)d_in[2];
  // d_in[3] = attn_mask (causal tril) - implemented analytically
  const float* q0_w   = (const float*)d_in[4];
  const float* kv0_w  = (const float*)d_in[5];
  const float* out0_w = (const float*)d_in[6];
  const float* q1_w   = (const float*)d_in[7];
  const float* kv1_w  = (const float*)d_in[8];
  const float* out1_w = (const float*)d_in[9];

  float* out  = (float*)d_out;
  float* out0 = out;                    // 4*768*2048 = 6291456
  float* out1 = out + 6291456;          // 4*256*1024 = 1048576
  float* idxp = out + 7340032;          // 4
  float* kout = out + 7340036;          // 4*1024*256 = 1048576
  float* vout = out + 8388612;          // 4*1024*256 = 1048576

  char* ws = (char*)d_ws;
  size_t off = 0;
  auto alloc = [&](size_t bytes){
    void* p = ws + off;
    off = (off + bytes + 255) & ~(size_t)255;
    return p;
  };
  u16* x0b  = (u16*)alloc((size_t)6291456 * 2);
  u16* x1b  = (u16*)alloc((size_t)1048576 * 2);
  u16* q0T  = (u16*)alloc((size_t)2048 * 2048 * 2);
  u16* kv0T = (u16*)alloc((size_t)512  * 2048 * 2);
  u16* q1T  = (u16*)alloc((size_t)2048 * 1024 * 2);
  u16* kv1T = (u16*)alloc((size_t)512  * 1024 * 2);
  u16* o0T  = (u16*)alloc((size_t)2048 * 2048 * 2);
  u16* o1T  = (u16*)alloc((size_t)1024 * 2048 * 2);
  u16* qbuf = (u16*)alloc((size_t)4096 * 2048 * 2);
  u16* kvbuf= (u16*)alloc((size_t)4096 * 512  * 2);
  u16* vTb  = (u16*)alloc((size_t)4 * 256 * 1024 * 2);
  u16* encb = (u16*)alloc((size_t)4096 * 2048 * 2);

  // 1. converts
  cvt_f32_bf16<<<6144, 256, 0, stream>>>(x0, x0b, 1572864);
  cvt_f32_bf16<<<1024, 256, 0, stream>>>(x1, x1b, 262144);
  // 2. weight transposes -> B^T bf16
  transpose_f32_bf16<<<dim3(64, 8, 8),  dim3(32,8), 0, stream>>>(q0_w,   q0T,  2048, 256);
  transpose_f32_bf16<<<dim3(64, 8, 2),  dim3(32,8), 0, stream>>>(kv0_w,  kv0T, 2048, 256);
  transpose_f32_bf16<<<dim3(32, 8, 8),  dim3(32,8), 0, stream>>>(q1_w,   q1T,  1024, 256);
  transpose_f32_bf16<<<dim3(32, 8, 2),  dim3(32,8), 0, stream>>>(kv1_w,  kv1T, 1024, 256);
  transpose_f32_bf16<<<dim3(64, 64, 1), dim3(32,8), 0, stream>>>(out0_w, o0T,  2048, 2048);
  transpose_f32_bf16<<<dim3(64, 32, 1), dim3(32,8), 0, stream>>>(out1_w, o1T,  2048, 1024);
  // 3. QKV projections (M/128 * N/128 blocks)
  gemm_bf16<<<384, 256, 0, stream>>>(x0b, 2048, 3072, 3072, 0, q0T, 2048,
                                     qbuf, nullptr, 2048, 768, 1024, 0, 2048, 2048);
  gemm_bf16<<<96,  256, 0, stream>>>(x0b, 2048, 3072, 3072, 0, kv0T, 2048,
                                     kvbuf, nullptr, 512, 768, 1024, 0, 512, 2048);
  gemm_bf16<<<128, 256, 0, stream>>>(x1b, 1024, 1024, 1024, 0, q1T, 1024,
                                     qbuf, nullptr, 2048, 256, 1024, 768, 2048, 1024);
  gemm_bf16<<<32,  256, 0, stream>>>(x1b, 1024, 1024, 1024, 0, kv1T, 1024,
                                     kvbuf, nullptr, 512, 256, 1024, 768, 512, 1024);
  // 4. RoPE + k/v/idx outputs
  rope_kernel<<<4096, 128, 0, stream>>>(qbuf, kvbuf, pos, kout, vout, idxp);
  // 5. V transpose for PV B-frags
  transpose_v<<<dim3(32, 8, 4), dim3(32,8), 0, stream>>>(kvbuf, vTb);
  // 6. attention
  attn_kernel<<<1024, 64, 0, stream>>>(qbuf, kvbuf, vTb, encb);
  // 7. output projections
  gemm_bf16<<<384, 256, 0, stream>>>(encb, 2048, 768, 1024, 0, o0T, 2048,
                                     nullptr, out0, 2048, 3072, 3072, 0, 2048, 2048);
  gemm_bf16<<<64,  256, 0, stream>>>(encb, 2048, 256, 1024, 768, o1T, 2048,
                                     nullptr, out1, 1024, 1024, 1024, 0, 1024, 2048);
}

// Round 2
// 373.762 us; speedup vs baseline: 1.1376x; 1.1376x over previous
//
#include <hip/hip_runtime.h>

typedef unsigned short u16;
typedef __attribute__((ext_vector_type(8))) short short8;
typedef __attribute__((ext_vector_type(4))) float f32x4;
typedef __attribute__((ext_vector_type(4))) unsigned short u16x4;

__device__ __forceinline__ u16 f2bf(float f){
  unsigned u = __float_as_uint(f);
  u += 0x7FFFu + ((u >> 16) & 1u);
  return (u16)(u >> 16);
}
__device__ __forceinline__ float bf2f(u16 h){
  return __uint_as_float(((unsigned)h) << 16);
}
__device__ __forceinline__ void gload16(const void* g, void* l){
  __builtin_amdgcn_global_load_lds((const __attribute__((address_space(1))) void*)g,
                                   (__attribute__((address_space(3))) void*)l, 16, 0, 0);
}
__device__ __forceinline__ f32x4 mfma16(short8 a, short8 b, f32x4 c){
  return __builtin_amdgcn_mfma_f32_16x16x32_bf16(a, b, c, 0, 0, 0);
}
__device__ __forceinline__ short8 ld8(const u16* p){
  return *reinterpret_cast<const short8*>(p);
}

// DPP 16-lane reductions (full-rate VALU, no ds_swizzle)
template<int CTRL>
__device__ __forceinline__ float dppf(float x){
  return __int_as_float(__builtin_amdgcn_update_dpp(0, __float_as_int(x), CTRL, 0xF, 0xF, true));
}
__device__ __forceinline__ float rmax16(float x){
  x = fmaxf(x, dppf<0xB1>(x));    // quad_perm [1,0,3,2]
  x = fmaxf(x, dppf<0x4E>(x));    // quad_perm [2,3,0,1]
  x = fmaxf(x, dppf<0x124>(x));   // row_ror:4
  x = fmaxf(x, dppf<0x128>(x));   // row_ror:8
  return x;
}
__device__ __forceinline__ float rsum16(float x){
  x += dppf<0xB1>(x);
  x += dppf<0x4E>(x);
  x += dppf<0x124>(x);
  x += dppf<0x128>(x);
  return x;
}

// ---------------- f32 -> bf16 convert (vectorized) ----------------
__global__ void cvt_f32_bf16(const float* __restrict__ s, u16* __restrict__ d, int n4){
  int i = blockIdx.x * 256 + threadIdx.x;
  if (i >= n4) return;
  float4 v = reinterpret_cast<const float4*>(s)[i];
  u16x4 o = { f2bf(v.x), f2bf(v.y), f2bf(v.z), f2bf(v.w) };
  reinterpret_cast<u16x4*>(d)[i] = o;
}

// ---------------- transpose-convert: per head [K][C] f32 -> [C][K] bf16 ----------------
__global__ void transpose_f32_bf16(const float* __restrict__ s, u16* __restrict__ d,
                                   int K, int C){
  __shared__ float t[32][33];
  size_t hoff = (size_t)blockIdx.z * K * C;
  const float* S = s + hoff;
  u16* D = d + hoff;
  int kb = blockIdx.x * 32, cb = blockIdx.y * 32;
  int tx = threadIdx.x, ty = threadIdx.y;
  #pragma unroll
  for (int i = ty; i < 32; i += 8)
    t[i][tx] = S[(size_t)(kb + i) * C + cb + tx];
  __syncthreads();
  #pragma unroll
  for (int i = ty; i < 32; i += 8)
    D[(size_t)(cb + i) * K + kb + tx] = f2bf(t[tx][i]);
}

// ---------------- bf16 GEMM, 128x128 tile, BK=32, global_load_lds ----------------
__global__ __launch_bounds__(256)
void gemm_bf16(const u16* __restrict__ A, int lda, int aS, int aT, int aOff,
               const u16* __restrict__ BT, int ldbt,
               u16* __restrict__ Cb, float* __restrict__ Cf, int ldc,
               int cS, int cT, int cOff, int N, int Kd){
  __shared__ __align__(16) u16 As[128*32];
  __shared__ __align__(16) u16 Bs[128*32];
  int ntx = N >> 7;
  int bm = blockIdx.x / ntx;
  int bn = blockIdx.x - bm * ntx;
  int row0 = bm << 7, col0 = bn << 7;
  size_t arow0 = (size_t)(row0 / aS) * aT + (row0 % aS) + aOff;
  size_t crow0 = (size_t)(row0 / cS) * cT + (row0 % cS) + cOff;
  const u16* Abase = A + arow0 * (size_t)lda;
  const u16* Bbase = BT + (size_t)col0 * ldbt;
  int tid = threadIdx.x;
  int w = tid >> 6, l = tid & 63;
  int wr = (w >> 1) << 6, wc = (w & 1) << 6;
  int lr = l & 15, lk = (l >> 4) << 3, lq = (l >> 4) << 2;
  f32x4 acc[4][4];
  #pragma unroll
  for (int m = 0; m < 4; m++)
    #pragma unroll
    for (int n = 0; n < 4; n++)
      acc[m][n] = (f32x4){0.f, 0.f, 0.f, 0.f};
  const u16* gA = Abase + (size_t)(tid >> 2) * lda + ((tid & 3) << 3);
  const u16* gB = Bbase + (size_t)(tid >> 2) * ldbt + ((tid & 3) << 3);
  char* lA = (char*)As + tid * 16;
  char* lB = (char*)Bs + tid * 16;
  size_t a64 = (size_t)64 * lda, b64 = (size_t)64 * ldbt;
  for (int k0 = 0; k0 < Kd; k0 += 32){
    gload16(gA + k0,       lA);
    gload16(gA + a64 + k0, lA + 4096);
    gload16(gB + k0,       lB);
    gload16(gB + b64 + k0, lB + 4096);
    __syncthreads();
    short8 af[4], bfr[4];
    #pragma unroll
    for (int m = 0; m < 4; m++)
      af[m] = ld8(&As[(wr + m*16 + lr)*32 + lk]);
    #pragma unroll
    for (int n = 0; n < 4; n++)
      bfr[n] = ld8(&Bs[(wc + n*16 + lr)*32 + lk]);
    #pragma unroll
    for (int m = 0; m < 4; m++)
      #pragma unroll
      for (int n = 0; n < 4; n++)
        acc[m][n] = mfma16(af[m], bfr[n], acc[m][n]);
    __syncthreads();
  }
  #pragma unroll
  for (int m = 0; m < 4; m++){
    #pragma unroll
    for (int i = 0; i < 4; i++){
      size_t r = crow0 + wr + m*16 + lq + i;
      if (Cb){
        #pragma unroll
        for (int n = 0; n < 4; n++)
          Cb[r*ldc + col0 + wc + n*16 + lr] = f2bf(acc[m][n][i]);
      } else {
        #pragma unroll
        for (int n = 0; n < 4; n++)
          Cf[r*ldc + col0 + wc + n*16 + lr] = acc[m][n][i];
      }
    }
  }
}

// ---------------- RoPE + k/v/idx outputs (qkv buffer, stride 2560) ----------------
__global__ void rope_kernel(u16* __restrict__ qkv, const int* __restrict__ positions,
                            float* __restrict__ k_out, float* __restrict__ v_out,
                            float* __restrict__ idx_out){
  int bt = blockIdx.x;
  int j = threadIdx.x;           // 0..127
  float pos = (float)positions[bt];
  float ts = powf(10000.0f, (float)j * 0.0078125f);
  float rad = pos / ts;
  float sn, cs;
  sincosf(rad, &sn, &cs);
  u16* q = qkv + (size_t)bt * 2560;
  #pragma unroll
  for (int n = 0; n < 8; n++){
    float x1 = bf2f(q[n*256 + j]);
    float x2 = bf2f(q[n*256 + 128 + j]);
    q[n*256 + j]       = f2bf((x1*cs - x2*sn) * 0.0625f);
    q[n*256 + 128 + j] = f2bf((x2*cs + x1*sn) * 0.0625f);
  }
  u16* kv = q + 2048;
  float x1 = bf2f(kv[j]), x2 = bf2f(kv[128 + j]);
  float k1 = x1*cs - x2*sn, k2 = x2*cs + x1*sn;
  kv[j] = f2bf(k1); kv[128 + j] = f2bf(k2);
  size_t ko = (size_t)bt * 256;
  k_out[ko + j] = k1;  k_out[ko + 128 + j] = k2;
  v_out[ko + j] = bf2f(kv[256 + j]);
  v_out[ko + 128 + j] = bf2f(kv[384 + j]);
  if (bt == 0 && j < 4) idx_out[j] = 1024.0f;
}

// ---------------- transpose V: qkv[:, 2304:2560] -> vT [B][256][1024] ----------------
__global__ void transpose_v(const u16* __restrict__ qkv, u16* __restrict__ vT){
  __shared__ u16 t[32][33];
  int b = blockIdx.z;
  int tb = blockIdx.x * 32, hb = blockIdx.y * 32;
  int tx = threadIdx.x, ty = threadIdx.y;
  #pragma unroll
  for (int i = ty; i < 32; i += 8)
    t[i][tx] = qkv[(size_t)(b*1024 + tb + i)*2560 + 2304 + hb + tx];
  __syncthreads();
  #pragma unroll
  for (int i = ty; i < 32; i += 8)
    vT[(size_t)(b*256 + hb + i)*1024 + tb + tx] = t[tx][i];
}

// ---------------- flash attention v2: 1 wave/block, 32 q-rows, KVBLK=64 ----------------
__global__ __launch_bounds__(64, 1)
void attn_kernel(const u16* __restrict__ qkv, const u16* __restrict__ vT,
                 u16* __restrict__ enc){
  int blk = blockIdx.x;
  int qt = blk & 31;
  int n  = (blk >> 5) & 7;
  int b  = blk >> 8;
  int l  = threadIdx.x;
  int lr = l & 15, lkq = (l >> 4) << 3, lq = (l >> 4) << 2;
  int q0 = qt * 32;
  int nkv = q0 + 32;
  const u16* qb = qkv + ((size_t)(b*1024 + q0)) * 2560 + n*256;
  short8 qf[2][8];
  #pragma unroll
  for (int rf = 0; rf < 2; rf++)
    #pragma unroll
    for (int hf = 0; hf < 8; hf++)
      qf[rf][hf] = ld8(qb + (size_t)(rf*16 + lr)*2560 + hf*32 + lkq);
  f32x4 o[2][16];
  #pragma unroll
  for (int rf = 0; rf < 2; rf++)
    #pragma unroll
    for (int hf = 0; hf < 16; hf++)
      o[rf][hf] = (f32x4){0.f,0.f,0.f,0.f};
  float mrow[2][4], lrow[2][4];
  #pragma unroll
  for (int rf = 0; rf < 2; rf++)
    #pragma unroll
    for (int i = 0; i < 4; i++){ mrow[rf][i] = -3.0e38f; lrow[rf][i] = 0.f; }
  const u16* kb = qkv + (size_t)(b*1024) * 2560 + 2048;
  const u16* vb = vT + (size_t)b * 256 * 1024;
  __shared__ __align__(16) u16 P[32*64];
  for (int kt = 0; kt < nkv; kt += 64){
    // ---- QK^T ----
    f32x4 s[2][4];
    #pragma unroll
    for (int rf = 0; rf < 2; rf++)
      #pragma unroll
      for (int cf = 0; cf < 4; cf++)
        s[rf][cf] = (f32x4){0.f,0.f,0.f,0.f};
    const u16* kr = kb + (size_t)(kt + lr) * 2560 + lkq;
    #pragma unroll
    for (int hf = 0; hf < 8; hf++){
      short8 k0 = ld8(kr + hf*32);
      short8 k1 = ld8(kr + (size_t)16*2560 + hf*32);
      short8 k2 = ld8(kr + (size_t)32*2560 + hf*32);
      short8 k3 = ld8(kr + (size_t)48*2560 + hf*32);
      #pragma unroll
      for (int rf = 0; rf < 2; rf++){
        s[rf][0] = mfma16(qf[rf][hf], k0, s[rf][0]);
        s[rf][1] = mfma16(qf[rf][hf], k1, s[rf][1]);
        s[rf][2] = mfma16(qf[rf][hf], k2, s[rf][2]);
        s[rf][3] = mfma16(qf[rf][hf], k3, s[rf][3]);
      }
    }
    // ---- causal mask (also kills cols >= nkv) ----
    if (kt + 64 > q0){
      #pragma unroll
      for (int rf = 0; rf < 2; rf++)
        #pragma unroll
        for (int cf = 0; cf < 4; cf++)
          #pragma unroll
          for (int i = 0; i < 4; i++){
            int row_g = q0 + rf*16 + lq + i;
            int col_g = kt + cf*16 + lr;
            if (col_g > row_g) s[rf][cf][i] = -1.0e30f;
          }
    }
    // ---- online softmax with defer-max (THR=8) ----
    float mx[2][4];
    #pragma unroll
    for (int rf = 0; rf < 2; rf++)
      #pragma unroll
      for (int i = 0; i < 4; i++)
        mx[rf][i] = rmax16(fmaxf(fmaxf(s[rf][0][i], s[rf][1][i]),
                                 fmaxf(s[rf][2][i], s[rf][3][i])));
    bool nd = false;
    #pragma unroll
    for (int rf = 0; rf < 2; rf++)
      #pragma unroll
      for (int i = 0; i < 4; i++)
        nd = nd || (mx[rf][i] > mrow[rf][i] + 8.f);
    if (__ballot(nd)){
      #pragma unroll
      for (int rf = 0; rf < 2; rf++)
        #pragma unroll
        for (int i = 0; i < 4; i++){
          float mn = fmaxf(mrow[rf][i], mx[rf][i]);
          float corr = __expf(mrow[rf][i] - mn);
          mrow[rf][i] = mn;
          lrow[rf][i] *= corr;
          #pragma unroll
          for (int hf = 0; hf < 16; hf++)
            o[rf][hf][i] *= corr;
        }
    }
    #pragma unroll
    for (int rf = 0; rf < 2; rf++)
      #pragma unroll
      for (int i = 0; i < 4; i++){
        float m = mrow[rf][i];
        float p0 = __expf(s[rf][0][i] - m);
        float p1 = __expf(s[rf][1][i] - m);
        float p2 = __expf(s[rf][2][i] - m);
        float p3 = __expf(s[rf][3][i] - m);
        s[rf][0][i] = p0; s[rf][1][i] = p1; s[rf][2][i] = p2; s[rf][3][i] = p3;
        lrow[rf][i] += rsum16(p0 + p1 + p2 + p3);
      }
    // ---- P -> LDS (XOR swizzled: byte ^= (row&7)<<4) ----
    asm volatile("s_waitcnt lgkmcnt(0)" ::: "memory");
    __builtin_amdgcn_sched_barrier(0);
    #pragma unroll
    for (int rf = 0; rf < 2; rf++)
      #pragma unroll
      for (int cf = 0; cf < 4; cf++)
        #pragma unroll
        for (int i = 0; i < 4; i++){
          int by = (((rf*16 + lq + i)*64 + cf*16 + lr) << 1) ^ (((lq + i) & 7) << 4);
          *(u16*)((char*)P + by) = f2bf(s[rf][cf][i]);
        }
    asm volatile("s_waitcnt lgkmcnt(0)" ::: "memory");
    __builtin_amdgcn_sched_barrier(0);
    short8 pa[2][2];
    #pragma unroll
    for (int rf = 0; rf < 2; rf++)
      #pragma unroll
      for (int kw = 0; kw < 2; kw++){
        int by = (((rf*16 + lr)*64 + kw*32 + lkq) << 1) ^ ((lr & 7) << 4);
        pa[rf][kw] = *(const short8*)((const char*)P + by);
      }
    __builtin_amdgcn_sched_barrier(0);
    // ---- PV ----
    #pragma unroll
    for (int hf = 0; hf < 16; hf++){
      const u16* vp = vb + (size_t)(hf*16 + lr)*1024 + kt + lkq;
      short8 v0 = ld8(vp);
      short8 v1 = ld8(vp + 32);
      o[0][hf] = mfma16(pa[0][0], v0, o[0][hf]);
      o[0][hf] = mfma16(pa[0][1], v1, o[0][hf]);
      o[1][hf] = mfma16(pa[1][0], v0, o[1][hf]);
      o[1][hf] = mfma16(pa[1][1], v1, o[1][hf]);
    }
  }
  u16* eb = enc + ((size_t)(b*1024 + q0)) * 2048 + n*256;
  float inv[2][4];
  #pragma unroll
  for (int rf = 0; rf < 2; rf++)
    #pragma unroll
    for (int i = 0; i < 4; i++)
      inv[rf][i] = 1.0f / lrow[rf][i];
  #pragma unroll
  for (int rf = 0; rf < 2; rf++)
    #pragma unroll
    for (int hf = 0; hf < 16; hf++)
      #pragma unroll
      for (int i = 0; i < 4; i++)
        eb[(size_t)(rf*16 + lq + i)*2048 + hf*16 + lr] = f2bf(o[rf][hf][i] * inv[rf][i]);
}

extern "C" void kernel_launch(void* const* d_in, const int* in_sizes, int n_in,
                              void* d_out, int out_size, void* d_ws, size_t ws_size,
                              hipStream_t stream){
  const float* x0     = (const float*)d_in[0];
  const float* x1     = (const float*)d_in[1];
  const int*   pos    = (const int*)d_in[2];
  const float* q0_w   = (const float*)d_in[4];
  const float* kv0_w  = (const float*)d_in[5];
  const float* out0_w = (const float*)d_in[6];
  const float* q1_w   = (const float*)d_in[7];
  const float* kv1_w  = (const float*)d_in[8];
  const float* out1_w = (const float*)d_in[9];

  float* out  = (float*)d_out;
  float* out0 = out;
  float* out1 = out + 6291456;
  float* idxp = out + 7340032;
  float* kout = out + 7340036;
  float* vout = out + 8388612;

  char* ws = (char*)d_ws;
  size_t off = 0;
  auto alloc = [&](size_t bytes){
    void* p = ws + off;
    off = (off + bytes + 255) & ~(size_t)255;
    return p;
  };
  u16* x0b   = (u16*)alloc((size_t)6291456 * 2);
  u16* x1b   = (u16*)alloc((size_t)1048576 * 2);
  u16* qkv0T = (u16*)alloc((size_t)2560 * 2048 * 2);
  u16* qkv1T = (u16*)alloc((size_t)2560 * 1024 * 2);
  u16* o0T   = (u16*)alloc((size_t)2048 * 2048 * 2);
  u16* o1T   = (u16*)alloc((size_t)1024 * 2048 * 2);
  u16* qkvb  = (u16*)alloc((size_t)4096 * 2560 * 2);
  u16* vTb   = (u16*)alloc((size_t)4 * 256 * 1024 * 2);
  u16* encb  = (u16*)alloc((size_t)4096 * 2048 * 2);

  cvt_f32_bf16<<<6144, 256, 0, stream>>>(x0, x0b, 1572864);
  cvt_f32_bf16<<<1024, 256, 0, stream>>>(x1, x1b, 262144);

  transpose_f32_bf16<<<dim3(64, 8, 8),  dim3(32,8), 0, stream>>>(q0_w,  qkv0T, 2048, 256);
  transpose_f32_bf16<<<dim3(64, 8, 2),  dim3(32,8), 0, stream>>>(kv0_w, qkv0T + (size_t)2048*2048, 2048, 256);
  transpose_f32_bf16<<<dim3(32, 8, 8),  dim3(32,8), 0, stream>>>(q1_w,  qkv1T, 1024, 256);
  transpose_f32_bf16<<<dim3(32, 8, 2),  dim3(32,8), 0, stream>>>(kv1_w, qkv1T + (size_t)2048*1024, 1024, 256);
  transpose_f32_bf16<<<dim3(64, 64, 1), dim3(32,8), 0, stream>>>(out0_w, o0T, 2048, 2048);
  transpose_f32_bf16<<<dim3(64, 32, 1), dim3(32,8), 0, stream>>>(out1_w, o1T, 2048, 1024);

  // merged q+kv projections (N=2560)
  gemm_bf16<<<480, 256, 0, stream>>>(x0b, 2048, 3072, 3072, 0, qkv0T, 2048,
                                     qkvb, nullptr, 2560, 768, 1024, 0, 2560, 2048);
  gemm_bf16<<<160, 256, 0, stream>>>(x1b, 1024, 1024, 1024, 0, qkv1T, 1024,
                                     qkvb, nullptr, 2560, 256, 1024, 768, 2560, 1024);

  rope_kernel<<<4096, 128, 0, stream>>>(qkvb, pos, kout, vout, idxp);
  transpose_v<<<dim3(32, 8, 4), dim3(32,8), 0, stream>>>(qkvb, vTb);
  attn_kernel<<<1024, 64, 0, stream>>>(qkvb, vTb, encb);

  gemm_bf16<<<384, 256, 0, stream>>>(encb, 2048, 768, 1024, 0, o0T, 2048,
                                     nullptr, out0, 2048, 3072, 3072, 0, 2048, 2048);
  gemm_bf16<<<64,  256, 0, stream>>>(encb, 2048, 256, 1024, 768, o1T, 2048,
                                     nullptr, out1, 1024, 1024, 1024, 0, 1024, 2048);
}